// Round 19
// baseline (7810.086 us; speedup 1.0000x reference)
//
#include <hip/hip_runtime.h>
#include <math.h>

#define BB 64      // batch
#define KK 4       // beam width
#define RR 256     // KK*BB rows
#define DD 512
#define HH 512
#define T3 1536
#define VV 50257
#define NSTR 393   // ceil(VV/128)

struct SRec {       // per (row, stripe) record, 48 B
  float v[4];       // stripe top-4 logits (desc, idx-asc on ties)
  int   ix[4];
  float ms;         // stripe max (== v[0])
  float pad;
  double S;         // sum expf(v - ms) over stripe, fp64 accumulated
};

// init: zero h buffer A, scores; curx from xs; bfrom = identity (so the
// gather-fused k_gru reads the zero state unpermuted at t=0).
__global__ __launch_bounds__(256) void k_init(const int* __restrict__ xs,
                                              float* __restrict__ hA,
                                              float* __restrict__ scores,
                                              int* __restrict__ curx,
                                              int* __restrict__ bfrom) {
  int i = blockIdx.x * 256 + threadIdx.x;
  if (i < HH * RR) hA[i] = 0.0f;
  if (i < RR) {
    scores[i] = 0.0f;
    curx[i] = xs[i & 63];
    bfrom[i] = i >> 6;   // identity: row s*64+b sourced from beam s
  }
}

// GRU for 256 beam-rows, fp32, fixed sequential k-order (deterministic, so
// bit-identical beam rows stay bit-identical). 1D grid 256.
// W tile staged in LDS once per kt (6 KB) + XCD-aware decode (v18,
// measured win). Beam gather fused; hin/hout double-buffered.
__global__ __launch_bounds__(256) void k_gru(const float* __restrict__ Etab,
                                             const float* __restrict__ Wih,
                                             const float* __restrict__ Whh,
                                             const float* __restrict__ bih,
                                             const float* __restrict__ bhh,
                                             const float* __restrict__ hin,
                                             float* __restrict__ hout,
                                             const int* __restrict__ curx,
                                             const int* __restrict__ bfrom) {
  const int n = blockIdx.x;          // 256 blocks
  const int cls = n & 7;
  const int m = n >> 3;              // 0..31
  const int jg = cls + 8 * (m & 7);  // 0..63 (siblings share n%8)
  const int rg = m >> 3;             // 0..3

  const int tid = threadIdx.x;
  const int jloc = tid & 7;
  const int bg = tid >> 3;
  const int j = jg * 8 + jloc;
  const int rowbase = rg * 64;
  const int b0 = bg * 2;  // local row pair within group

  __shared__ float xe[64 * 33];
  __shared__ float hp[64 * 33];
  __shared__ float wl[6][32][8];   // 6 KB W tile: [gate][kk][jloc]
  __shared__ int xl[64];
  __shared__ int bf[64];
  if (tid < 64) {
    xl[tid] = curx[rowbase + tid];
    bf[tid] = bfrom[rowbase + tid];
  }

  float a[12];
#pragma unroll
  for (int i = 0; i < 12; ++i) a[i] = 0.0f;

  const int wkk = tid >> 3;   // 0..31: k within tile (for W staging)
  const int wjl = tid & 7;    // 0..7 : j within tile

  for (int kt = 0; kt < 16; ++kt) {
    __syncthreads();
    const int kb = kt * 32;
#pragma unroll
    for (int i = 0; i < 8; ++i) {
      int idx = i * 256 + tid;
      int b = idx >> 5, kk = idx & 31;
      xe[b * 33 + kk] = Etab[(size_t)xl[b] * DD + kb + kk];
    }
#pragma unroll
    for (int i = 0; i < 8; ++i) {
      int idx = i * 256 + tid;
      int kk = idx >> 6, bl = idx & 63;
      // gathered read: old hCur[j][rowbase+bl] == hin[j][bf*64 + bl]
      hp[bl * 33 + kk] = hin[(size_t)(kb + kk) * RR + bf[bl] * 64 + bl];
    }
    // W tile: gate g (0..2 = Wih r/z/g, 3..5 = Whh r/z/g), 256 thr/gate.
#pragma unroll
    for (int g = 0; g < 6; ++g) {
      const float* Wsrc = (g < 3) ? Wih : Whh;
      const int gc = (g % 3) * HH;
      wl[g][wkk][wjl] = Wsrc[(size_t)(kb + wkk) * T3 + gc + jg * 8 + wjl];
    }
    __syncthreads();
#pragma unroll 4
    for (int kk = 0; kk < 32; ++kk) {
      float wir = wl[0][kk][jloc];
      float wiz = wl[1][kk][jloc];
      float wig = wl[2][kk][jloc];
      float whr = wl[3][kk][jloc];
      float whz = wl[4][kk][jloc];
      float whg = wl[5][kk][jloc];
      float x0v = xe[b0 * 33 + kk];
      float x1v = xe[(b0 + 1) * 33 + kk];
      float h0v = hp[b0 * 33 + kk];
      float h1v = hp[(b0 + 1) * 33 + kk];
      a[0] += x0v * wir; a[1]  += x0v * wiz; a[2]  += x0v * wig;
      a[3] += h0v * whr; a[4]  += h0v * whz; a[5]  += h0v * whg;
      a[6] += x1v * wir; a[7]  += x1v * wiz; a[8]  += x1v * wig;
      a[9] += h1v * whr; a[10] += h1v * whz; a[11] += h1v * whg;
    }
  }

  const float bir = bih[j], biz = bih[HH + j], big = bih[2 * HH + j];
  const float bhr = bhh[j], bhz = bhh[HH + j], bhg = bhh[2 * HH + j];
#pragma unroll
  for (int p = 0; p < 2; ++p) {
    const int row = rowbase + b0 + p;
    float ir = a[6 * p + 0] + bir;
    float iz = a[6 * p + 1] + biz;
    float ig = a[6 * p + 2] + big;
    float hr = a[6 * p + 3] + bhr;
    float hz = a[6 * p + 4] + bhz;
    float hg = a[6 * p + 5] + bhg;
    float r = 1.0f / (1.0f + expf(-(ir + hr)));
    float z = 1.0f / (1.0f + expf(-(iz + hz)));
    float n2 = tanhf(ig + r * hg);
    float hprev = hin[(size_t)j * RR + bf[b0 + p] * 64 + (b0 + p)];
    hout[(size_t)j * RR + row] = (1.0f - z) * n2 + z * hprev;
  }
}

// Merge two sorted-4 lists (desc value, asc index on ties), keep top-4.
__device__ __forceinline__ void merge44(float* v, int* ix, const float* ov, const int* oix) {
  float rv[4]; int rix[4];
  int a = 0, b = 0;
#pragma unroll
  for (int t = 0; t < 4; ++t) {
    bool ta;
    if (a >= 4) ta = false;
    else if (b >= 4) ta = true;
    else ta = (v[a] > ov[b]) || (v[a] == ov[b] && ix[a] < oix[b]);
    if (ta) { rv[t] = v[a]; rix[t] = ix[a]; ++a; }
    else    { rv[t] = ov[b]; rix[t] = oix[b]; ++b; }
  }
#pragma unroll
  for (int t = 0; t < 4; ++t) { v[t] = rv[t]; ix[t] = rix[t]; }
}

// logits (fp32) for 256 rows; per (row, 128-col stripe): top-4 by value
// (idx-asc ties) + stripe max + stripe exp-sum.
// v20: SAME per-wave code as v14/v19 (mapped optimum: 8 rows/wave), but
// block = ONE WAVE (64 threads), grid 12800 (12576 active). k_logits has
// zero inter-wave coupling (no barriers, each wave owns its rows), so
// block size is purely a scheduling knob: 4-wave blocks at 12.3 blocks/CU
// gave only ~48% occupancy (coarse granularity -> ramp/drain tail with
// partially filled CUs). 1-wave blocks pack finer and shrink the tail.
// Numerics: per-wave instruction stream identical -> bit-identical SRecs.
__global__ __launch_bounds__(64) void k_logits(const float* __restrict__ Wout,
                                               const float* __restrict__ bout,
                                               const float* __restrict__ hStage,
                                               SRec* __restrict__ sbuf) {
  // XCD-aware decode: same stripe -> same XCD class (n%8 == s%8).
  const int n = blockIdx.x;
  const int cls = n & 7;
  const int m = n >> 3;           // 0..1599
  const int s = cls + 8 * (m >> 5);
  const int y = m & 31;           // rowgroup (8 rows each)
  if (s >= NSTR) return;          // idle tail blocks

  const int ct = threadIdx.x;     // 0..63 (one wave)
  const int scol = s * 128;
  const int c0 = scol + ct;
  const bool okA = (c0 < VV);
  const bool okB = (c0 + 64 < VV);
  const int cA = okA ? c0 : (VV - 1);
  const int cB = okB ? (c0 + 64) : (VV - 1);
  // wave-uniform row base (forced uniform -> broadcast loads for h)
  const int rowU = __builtin_amdgcn_readfirstlane(y * 8);

  float acc[8][2];
#pragma unroll
  for (int ri = 0; ri < 8; ++ri) { acc[ri][0] = 0.0f; acc[ri][1] = 0.0f; }

  float wA0[8], wB0[8], wA1[8], wB1[8];

  auto loadW = [&](float* wA, float* wB, int kb) {
#pragma unroll
    for (int i = 0; i < 8; ++i) {
      // uniform SGPR row base + loop-invariant per-lane index
      const float* __restrict__ wr = Wout + (size_t)(kb + i) * VV;
      wA[i] = wr[cA];
      wB[i] = wr[cB];
    }
  };
  auto fmaC = [&](const float* wA, const float* wB, int kb) {
#pragma unroll
    for (int i = 0; i < 8; ++i) {
      // 8 h values for this wave's rows: one 32-B aligned uniform fetch
      const float4* hg = reinterpret_cast<const float4*>(
          hStage + (size_t)(kb + i) * RR + rowU);
      float4 h0 = hg[0], h1 = hg[1];
      float hr[8] = {h0.x, h0.y, h0.z, h0.w, h1.x, h1.y, h1.z, h1.w};
#pragma unroll
      for (int ri = 0; ri < 8; ++ri) {
        acc[ri][0] += hr[ri] * wA[i];
        acc[ri][1] += hr[ri] * wB[i];
      }
    }
  };

  loadW(wA0, wB0, 0);
  for (int c = 0; c < 64; c += 2) {         // 64 groups of 8 k
    loadW(wA1, wB1, (c + 1) * 8);           // prefetch odd group
    fmaC(wA0, wB0, c * 8);                  // consume even group
    if (c + 2 < 64) loadW(wA0, wB0, (c + 2) * 8);  // prefetch next even
    fmaC(wA1, wB1, (c + 1) * 8);            // consume odd group
  }

  const float boA = bout[cA];
  const float boB = bout[cB];
#pragma unroll
  for (int ri = 0; ri < 8; ++ri) {          // FULL unroll: static acc indices
    float vA = okA ? (acc[ri][0] + boA) : -INFINITY;
    float vB = okB ? (acc[ri][1] + boB) : -INFINITY;
    // per-lane sorted-2 (pad to 4); cA < cB so tie keeps cA first
    float v[4]; int ix[4];
    if (vB > vA) { v[0] = vB; ix[0] = c0 + 64; v[1] = vA; ix[1] = okA ? c0 : 0x7fffffff; }
    else         { v[0] = vA; ix[0] = okA ? c0 : 0x7fffffff; v[1] = vB; ix[1] = okB ? (c0 + 64) : 0x7fffffff; }
    v[2] = -INFINITY; ix[2] = 0x7fffffff;
    v[3] = -INFINITY; ix[3] = 0x7fffffff;
    // butterfly merge across 64 lanes -> wave-wide top-4 (all lanes agree)
#pragma unroll
    for (int mm = 1; mm < 64; mm <<= 1) {
      float ov[4]; int oix[4];
#pragma unroll
      for (int jj = 0; jj < 4; ++jj) {
        ov[jj] = __shfl_xor(v[jj], mm, 64);
        oix[jj] = __shfl_xor(ix[jj], mm, 64);
      }
      merge44(v, ix, ov, oix);
    }
    const float ms = v[0];
    double sl = 0.0;
    if (okA) sl += (double)expf(vA - ms);
    if (okB) sl += (double)expf(vB - ms);
#pragma unroll
    for (int mm = 1; mm < 64; mm <<= 1) sl += __shfl_xor(sl, mm, 64);
    if (ct == 0) {
      const int row = rowU + ri;
      SRec* rec = &sbuf[(size_t)row * NSTR + s];
#pragma unroll
      for (int jj = 0; jj < 4; ++jj) { rec->v[jj] = v[jj]; rec->ix[jj] = ix[jj]; }
      rec->ms = ms;
      rec->S = sl;
    }
  }
}

// Merge a sorted-4 list into a sorted-8 list (keep top-8).
__device__ inline void merge84(float* v, int* ix, const float* ov, const int* oix) {
  float rv[8]; int rix[8];
  int a = 0, b = 0;
#pragma unroll
  for (int t = 0; t < 8; ++t) {
    bool ta;
    if (a >= 8) ta = false;
    else if (b >= 4) ta = true;
    else ta = (v[a] > ov[b]) || (v[a] == ov[b] && ix[a] < oix[b]);
    if (ta) { rv[t] = v[a]; rix[t] = ix[a]; ++a; }
    else    { rv[t] = ov[b]; rix[t] = oix[b]; ++b; }
  }
#pragma unroll
  for (int t = 0; t < 8; ++t) { v[t] = rv[t]; ix[t] = rix[t]; }
}

__device__ inline void merge88(float* v, int* ix, const float* ov, const int* oix) {
  float rv[8]; int rix[8];
  int a = 0, b = 0;
#pragma unroll
  for (int t = 0; t < 8; ++t) {
    bool ta;
    if (a >= 8) ta = false;
    else if (b >= 8) ta = true;
    else ta = (v[a] > ov[b]) || (v[a] == ov[b] && ix[a] < oix[b]);
    if (ta) { rv[t] = v[a]; rix[t] = ix[a]; ++a; }
    else    { rv[t] = ov[b]; rix[t] = oix[b]; ++b; }
  }
#pragma unroll
  for (int t = 0; t < 8; ++t) { v[t] = rv[t]; ix[t] = rix[t]; }
}

// Per row: global top-8 by raw value, fp64 Z, then emulate fp32 log_softmax
// q = fl32(fl32(v-m) - L32) and output top-4 by (q desc, idx asc).
__global__ __launch_bounds__(64) void k_merge(const SRec* __restrict__ sbuf,
                                              float* __restrict__ topq,
                                              int* __restrict__ topi) {
  const int row = blockIdx.x;
  const int l = threadIdx.x;
  float lv[8]; int li[8];
#pragma unroll
  for (int jj = 0; jj < 8; ++jj) { lv[jj] = -INFINITY; li[jj] = 0x7fffffff; }
  float lms[7]; double lS[7];
  int ns = 0;
  for (int s = l; s < NSTR; s += 64) {
    const SRec* rec = &sbuf[(size_t)row * NSTR + s];
    float mv[4]; int mi[4];
#pragma unroll
    for (int jj = 0; jj < 4; ++jj) { mv[jj] = rec->v[jj]; mi[jj] = rec->ix[jj]; }
    lms[ns] = rec->ms;
    lS[ns] = rec->S;
    ++ns;
    merge84(lv, li, mv, mi);
  }
#pragma unroll
  for (int m = 1; m < 64; m <<= 1) {
    float ov[8]; int oi[8];
#pragma unroll
    for (int jj = 0; jj < 8; ++jj) {
      ov[jj] = __shfl_xor(lv[jj], m, 64);
      oi[jj] = __shfl_xor(li[jj], m, 64);
    }
    merge88(lv, li, ov, oi);
  }
  const float mg = lv[0];  // global max logit
  double Z = 0.0;
  for (int i = 0; i < ns; ++i) Z += lS[i] * (double)expf(lms[i] - mg);
#pragma unroll
  for (int m = 1; m < 64; m <<= 1) Z += __shfl_xor(Z, m, 64);
  const float Zf = (float)Z;
  const float L32 = (float)log((double)Zf);
  // fp32-quantized logp for top-8, re-sort by (q desc, idx asc)
  float q[8];
#pragma unroll
  for (int jj = 0; jj < 8; ++jj) {
    float g = lv[jj] - mg;   // fp32 sub
    q[jj] = g - L32;         // fp32 sub -> the ref's logp quantization
  }
  // insertion sort of 8 (full order comparator: q desc, idx asc)
  float sq[8]; int si[8];
#pragma unroll
  for (int jj = 0; jj < 8; ++jj) {
    float cv = q[jj]; int ci = li[jj];
    int pos = jj;
    for (int kk2 = 0; kk2 < jj; ++kk2) {
      if (cv > sq[kk2] || (cv == sq[kk2] && ci < si[kk2])) { pos = kk2; break; }
    }
    for (int kk2 = jj; kk2 > pos; --kk2) { sq[kk2] = sq[kk2 - 1]; si[kk2] = si[kk2 - 1]; }
    sq[pos] = cv; si[pos] = ci;
  }
  if (l == 0) {
#pragma unroll
    for (int jj = 0; jj < 4; ++jj) {
      topq[row * 4 + jj] = sq[jj];
      topi[row * 4 + jj] = si[jj];
    }
  }
}

// Fused beam transition + sequence gather (one launch instead of two).
// Threads 0..63: k_beam logic (trans top-4, stable flat-index ties),
// results published via LDS; after barrier all 256 threads do the
// sequence copy + append (k_seq logic).
__global__ __launch_bounds__(256) void k_beamseq(const float* __restrict__ topq,
                                                 const int* __restrict__ topi,
                                                 float* __restrict__ scores,
                                                 int* __restrict__ curx,
                                                 int* __restrict__ bfrom,
                                                 const int* __restrict__ src,
                                                 int* __restrict__ dst,
                                                 int t, int T) {
  const int tid = threadIdx.x;
  __shared__ int sh_bf[RR];
  __shared__ int sh_cx[RR];

  if (tid < 64) {
    const int b = tid;  // 0..63
    float sc[4];
#pragma unroll
    for (int f = 0; f < 4; ++f) sc[f] = scores[f * 64 + b];
    float tv[16];
#pragma unroll
    for (int f = 0; f < 4; ++f)
#pragma unroll
      for (int to = 0; to < 4; ++to)
        tv[f * 4 + to] = sc[f] + topq[(f * 64 + b) * 4 + to];  // fp32 add

    float ov[4]; int ord[4]; int cnt = 0;
#pragma unroll
    for (int flat = 0; flat < 16; ++flat) {
      float v = tv[flat];
      int pos = -1;
      for (int j = 0; j < cnt; ++j)
        if (v > ov[j]) { pos = j; break; }   // strict: stable on equals
      if (pos < 0) {
        if (cnt < 4) { ov[cnt] = v; ord[cnt] = flat; ++cnt; }
      } else {
        int last = (cnt < 4) ? cnt : 3;
        for (int j = last; j > pos; --j) { ov[j] = ov[j - 1]; ord[j] = ord[j - 1]; }
        ov[pos] = v; ord[pos] = flat;
        if (cnt < 4) ++cnt;
      }
    }
#pragma unroll
    for (int s = 0; s < 4; ++s) {
      int flat = ord[s];
      int f = flat >> 2, to = flat & 3;
      int tok = topi[(f * 64 + b) * 4 + to];
      scores[s * 64 + b] = ov[s];
      curx[s * 64 + b] = tok;
      bfrom[s * 64 + b] = f;
      sh_bf[s * 64 + b] = f;
      sh_cx[s * 64 + b] = tok;
    }
  }
  __syncthreads();

  const int s2 = tid >> 6, b2 = tid & 63;
  const int bf2 = sh_bf[s2 * 64 + b2];
  for (int u = 0; u < t; ++u)
    dst[(b2 * KK + s2) * T + u] = src[(b2 * KK + bf2) * T + u];
  dst[(b2 * KK + s2) * T + t] = sh_cx[s2 * 64 + b2];
}

__global__ __launch_bounds__(256) void k_out(const int* __restrict__ seqs,
                                             int* __restrict__ outp, int T) {
  int idx = blockIdx.x * 256 + threadIdx.x;
  if (idx < BB * T) {
    int b = idx / T, u = idx % T;
    outp[b * T + u] = seqs[(b * KK + 0) * T + u];
  }
}

extern "C" void kernel_launch(void* const* d_in, const int* in_sizes, int n_in,
                              void* d_out, int out_size, void* d_ws, size_t ws_size,
                              hipStream_t stream) {
  (void)in_sizes; (void)n_in; (void)ws_size;
  const int* xs = (const int*)d_in[0];
  const float* Etab = (const float*)d_in[1];
  const float* Wih = (const float*)d_in[2];
  const float* Whh = (const float*)d_in[3];
  const float* bih = (const float*)d_in[4];
  const float* bhh = (const float*)d_in[5];
  const float* Wout = (const float*)d_in[6];
  const float* bout = (const float*)d_in[7];
  int* outp = (int*)d_out;
  const int T = out_size / BB;  // 16

  // workspace carve (~6 MB)
  SRec* sbuf = (SRec*)d_ws;                       // 256*393*48 B
  float* hA = (float*)(sbuf + (size_t)RR * NSTR); // h double-buffer A
  float* hB = hA + (size_t)HH * RR;               // h double-buffer B
  float* topq = hB + (size_t)HH * RR;             // RR*4 f
  int* topi = (int*)(topq + RR * 4);              // RR*4 i
  float* scores = (float*)(topi + RR * 4);        // RR f
  int* curx = (int*)(scores + RR);                // RR i
  int* bfrom = curx + RR;                         // RR i
  int* seqA = bfrom + RR;                         // BB*KK*T i
  int* seqB = seqA + BB * KK * T;                 // BB*KK*T i

  k_init<<<dim3(512), dim3(256), 0, stream>>>(xs, hA, scores, curx, bfrom);
  for (int t = 0; t < T; ++t) {
    int* ssrc = (t % 2 == 0) ? seqA : seqB;
    int* sdst = (t % 2 == 0) ? seqB : seqA;
    float* hin = (t & 1) ? hB : hA;   // previous step's (ungathered) h
    float* hout = (t & 1) ? hA : hB;  // this step's new h
    k_gru<<<dim3(256), dim3(256), 0, stream>>>(Etab, Wih, Whh, bih, bhh,
                                               hin, hout, curx, bfrom);
    k_logits<<<dim3(12800), dim3(64), 0, stream>>>(Wout, bout, hout, sbuf);
    k_merge<<<dim3(RR), dim3(64), 0, stream>>>(sbuf, topq, topi);
    k_beamseq<<<dim3(1), dim3(256), 0, stream>>>(topq, topi, scores, curx,
                                                 bfrom, ssrc, sdst, t, T);
  }
  int* sfin = (T % 2 == 0) ? seqA : seqB;
  k_out<<<dim3((BB * T + 255) / 256), dim3(256), 0, stream>>>(sfin, outp, T);
}

// Round 20
// 7525.839 us; speedup vs baseline: 1.0378x; 1.0378x over previous
//
#include <hip/hip_runtime.h>
#include <math.h>

#define BB 64      // batch
#define KK 4       // beam width
#define RR 256     // KK*BB rows
#define DD 512
#define HH 512
#define T3 1536
#define VV 50257
#define NSTR 393   // ceil(VV/128)

struct SRec {       // per (row, stripe) record, 48 B
  float v[4];       // stripe top-4 logits (desc, idx-asc on ties)
  int   ix[4];
  float ms;         // stripe max (== v[0])
  float pad;
  double S;         // sum expf(v - ms) over stripe, fp64 accumulated
};

// init: zero h buffer A, scores; curx from xs; bfrom = identity (so the
// gather-fused k_gru reads the zero state unpermuted at t=0).
__global__ __launch_bounds__(256) void k_init(const int* __restrict__ xs,
                                              float* __restrict__ hA,
                                              float* __restrict__ scores,
                                              int* __restrict__ curx,
                                              int* __restrict__ bfrom) {
  int i = blockIdx.x * 256 + threadIdx.x;
  if (i < HH * RR) hA[i] = 0.0f;
  if (i < RR) {
    scores[i] = 0.0f;
    curx[i] = xs[i & 63];
    bfrom[i] = i >> 6;   // identity: row s*64+b sourced from beam s
  }
}

// GRU for 256 beam-rows, fp32, fixed sequential k-order (deterministic, so
// bit-identical beam rows stay bit-identical). 1D grid 256.
// W tile staged in LDS once per kt (6 KB) + XCD-aware decode (v18,
// measured win). Beam gather fused; hin/hout double-buffered.
__global__ __launch_bounds__(256) void k_gru(const float* __restrict__ Etab,
                                             const float* __restrict__ Wih,
                                             const float* __restrict__ Whh,
                                             const float* __restrict__ bih,
                                             const float* __restrict__ bhh,
                                             const float* __restrict__ hin,
                                             float* __restrict__ hout,
                                             const int* __restrict__ curx,
                                             const int* __restrict__ bfrom) {
  const int n = blockIdx.x;          // 256 blocks
  const int cls = n & 7;
  const int m = n >> 3;              // 0..31
  const int jg = cls + 8 * (m & 7);  // 0..63 (siblings share n%8)
  const int rg = m >> 3;             // 0..3

  const int tid = threadIdx.x;
  const int jloc = tid & 7;
  const int bg = tid >> 3;
  const int j = jg * 8 + jloc;
  const int rowbase = rg * 64;
  const int b0 = bg * 2;  // local row pair within group

  __shared__ float xe[64 * 33];
  __shared__ float hp[64 * 33];
  __shared__ float wl[6][32][8];   // 6 KB W tile: [gate][kk][jloc]
  __shared__ int xl[64];
  __shared__ int bf[64];
  if (tid < 64) {
    xl[tid] = curx[rowbase + tid];
    bf[tid] = bfrom[rowbase + tid];
  }

  float a[12];
#pragma unroll
  for (int i = 0; i < 12; ++i) a[i] = 0.0f;

  const int wkk = tid >> 3;   // 0..31: k within tile (for W staging)
  const int wjl = tid & 7;    // 0..7 : j within tile

  for (int kt = 0; kt < 16; ++kt) {
    __syncthreads();
    const int kb = kt * 32;
#pragma unroll
    for (int i = 0; i < 8; ++i) {
      int idx = i * 256 + tid;
      int b = idx >> 5, kk = idx & 31;
      xe[b * 33 + kk] = Etab[(size_t)xl[b] * DD + kb + kk];
    }
#pragma unroll
    for (int i = 0; i < 8; ++i) {
      int idx = i * 256 + tid;
      int kk = idx >> 6, bl = idx & 63;
      // gathered read: old hCur[j][rowbase+bl] == hin[j][bf*64 + bl]
      hp[bl * 33 + kk] = hin[(size_t)(kb + kk) * RR + bf[bl] * 64 + bl];
    }
    // W tile: gate g (0..2 = Wih r/z/g, 3..5 = Whh r/z/g), 256 thr/gate.
#pragma unroll
    for (int g = 0; g < 6; ++g) {
      const float* Wsrc = (g < 3) ? Wih : Whh;
      const int gc = (g % 3) * HH;
      wl[g][wkk][wjl] = Wsrc[(size_t)(kb + wkk) * T3 + gc + jg * 8 + wjl];
    }
    __syncthreads();
#pragma unroll 4
    for (int kk = 0; kk < 32; ++kk) {
      float wir = wl[0][kk][jloc];
      float wiz = wl[1][kk][jloc];
      float wig = wl[2][kk][jloc];
      float whr = wl[3][kk][jloc];
      float whz = wl[4][kk][jloc];
      float whg = wl[5][kk][jloc];
      float x0v = xe[b0 * 33 + kk];
      float x1v = xe[(b0 + 1) * 33 + kk];
      float h0v = hp[b0 * 33 + kk];
      float h1v = hp[(b0 + 1) * 33 + kk];
      a[0] += x0v * wir; a[1]  += x0v * wiz; a[2]  += x0v * wig;
      a[3] += h0v * whr; a[4]  += h0v * whz; a[5]  += h0v * whg;
      a[6] += x1v * wir; a[7]  += x1v * wiz; a[8]  += x1v * wig;
      a[9] += h1v * whr; a[10] += h1v * whz; a[11] += h1v * whg;
    }
  }

  const float bir = bih[j], biz = bih[HH + j], big = bih[2 * HH + j];
  const float bhr = bhh[j], bhz = bhh[HH + j], bhg = bhh[2 * HH + j];
#pragma unroll
  for (int p = 0; p < 2; ++p) {
    const int row = rowbase + b0 + p;
    float ir = a[6 * p + 0] + bir;
    float iz = a[6 * p + 1] + biz;
    float ig = a[6 * p + 2] + big;
    float hr = a[6 * p + 3] + bhr;
    float hz = a[6 * p + 4] + bhz;
    float hg = a[6 * p + 5] + bhg;
    float r = 1.0f / (1.0f + expf(-(ir + hr)));
    float z = 1.0f / (1.0f + expf(-(iz + hz)));
    float n2 = tanhf(ig + r * hg);
    float hprev = hin[(size_t)j * RR + bf[b0 + p] * 64 + (b0 + p)];
    hout[(size_t)j * RR + row] = (1.0f - z) * n2 + z * hprev;
  }
}

// Merge two sorted-4 lists (desc value, asc index on ties), keep top-4.
__device__ __forceinline__ void merge44(float* v, int* ix, const float* ov, const int* oix) {
  float rv[4]; int rix[4];
  int a = 0, b = 0;
#pragma unroll
  for (int t = 0; t < 4; ++t) {
    bool ta;
    if (a >= 4) ta = false;
    else if (b >= 4) ta = true;
    else ta = (v[a] > ov[b]) || (v[a] == ov[b] && ix[a] < oix[b]);
    if (ta) { rv[t] = v[a]; rix[t] = ix[a]; ++a; }
    else    { rv[t] = ov[b]; rix[t] = oix[b]; ++b; }
  }
#pragma unroll
  for (int t = 0; t < 4; ++t) { v[t] = rv[t]; ix[t] = rix[t]; }
}

// logits (fp32) for 256 rows; per (row, 128-col stripe): top-4 by value
// (idx-asc ties) + stripe max + stripe exp-sum. Block 256 = 4 waves x 8
// rows (32 rows/block), grid 3200 (3144 active).
// v21 = byte-exact v19 (the measured best: 429-436 us steady, 7.53 ms
// total). Lever map closed: rows/wave curve (16/8/4 = 535/425/510),
// W-residency (null), pk_fma (null), h-LDS (regressed), launch_bounds
// hint (null), address association (null), 1-wave blocks (regressed,
// occupancy pinned ~49% regardless of granularity). This is the
// structure's practical floor under the bit-exact fmac-chain contract.
__global__ __launch_bounds__(256) void k_logits(const float* __restrict__ Wout,
                                                const float* __restrict__ bout,
                                                const float* __restrict__ hStage,
                                                SRec* __restrict__ sbuf) {
  // XCD-aware decode: same stripe -> same XCD class (n%8 == s%8).
  const int n = blockIdx.x;
  const int cls = n & 7;
  const int m = n >> 3;           // 0..399
  const int s = cls + 8 * (m >> 3);
  const int y = m & 7;            // rowgroup (32 rows each)
  if (s >= NSTR) return;          // idle tail blocks

  const int tid = threadIdx.x;
  const int wid = tid >> 6;       // wave -> rows rowU..rowU+7
  const int ct = tid & 63;
  const int scol = s * 128;
  const int c0 = scol + ct;
  const bool okA = (c0 < VV);
  const bool okB = (c0 + 64 < VV);
  const int cA = okA ? c0 : (VV - 1);
  const int cB = okB ? (c0 + 64) : (VV - 1);
  // wave-uniform row base (forced uniform -> broadcast loads for h)
  const int rowU = __builtin_amdgcn_readfirstlane(y * 32 + wid * 8);

  float acc[8][2];
#pragma unroll
  for (int ri = 0; ri < 8; ++ri) { acc[ri][0] = 0.0f; acc[ri][1] = 0.0f; }

  float wA0[8], wB0[8], wA1[8], wB1[8];

  auto loadW = [&](float* wA, float* wB, int kb) {
#pragma unroll
    for (int i = 0; i < 8; ++i) {
      // uniform SGPR row base + loop-invariant per-lane index
      const float* __restrict__ wr = Wout + (size_t)(kb + i) * VV;
      wA[i] = wr[cA];
      wB[i] = wr[cB];
    }
  };
  auto fmaC = [&](const float* wA, const float* wB, int kb) {
#pragma unroll
    for (int i = 0; i < 8; ++i) {
      // 8 h values for this wave's rows: one 32-B aligned uniform fetch
      const float4* hg = reinterpret_cast<const float4*>(
          hStage + (size_t)(kb + i) * RR + rowU);
      float4 h0 = hg[0], h1 = hg[1];
      float hr[8] = {h0.x, h0.y, h0.z, h0.w, h1.x, h1.y, h1.z, h1.w};
#pragma unroll
      for (int ri = 0; ri < 8; ++ri) {
        acc[ri][0] += hr[ri] * wA[i];
        acc[ri][1] += hr[ri] * wB[i];
      }
    }
  };

  loadW(wA0, wB0, 0);
  for (int c = 0; c < 64; c += 2) {         // 64 groups of 8 k
    loadW(wA1, wB1, (c + 1) * 8);           // prefetch odd group
    fmaC(wA0, wB0, c * 8);                  // consume even group
    if (c + 2 < 64) loadW(wA0, wB0, (c + 2) * 8);  // prefetch next even
    fmaC(wA1, wB1, (c + 1) * 8);            // consume odd group
  }

  const float boA = bout[cA];
  const float boB = bout[cB];
#pragma unroll
  for (int ri = 0; ri < 8; ++ri) {          // FULL unroll: static acc indices
    float vA = okA ? (acc[ri][0] + boA) : -INFINITY;
    float vB = okB ? (acc[ri][1] + boB) : -INFINITY;
    // per-lane sorted-2 (pad to 4); cA < cB so tie keeps cA first
    float v[4]; int ix[4];
    if (vB > vA) { v[0] = vB; ix[0] = c0 + 64; v[1] = vA; ix[1] = okA ? c0 : 0x7fffffff; }
    else         { v[0] = vA; ix[0] = okA ? c0 : 0x7fffffff; v[1] = vB; ix[1] = okB ? (c0 + 64) : 0x7fffffff; }
    v[2] = -INFINITY; ix[2] = 0x7fffffff;
    v[3] = -INFINITY; ix[3] = 0x7fffffff;
    // butterfly merge across 64 lanes -> wave-wide top-4 (all lanes agree)
#pragma unroll
    for (int mm = 1; mm < 64; mm <<= 1) {
      float ov[4]; int oix[4];
#pragma unroll
      for (int jj = 0; jj < 4; ++jj) {
        ov[jj] = __shfl_xor(v[jj], mm, 64);
        oix[jj] = __shfl_xor(ix[jj], mm, 64);
      }
      merge44(v, ix, ov, oix);
    }
    const float ms = v[0];
    double sl = 0.0;
    if (okA) sl += (double)expf(vA - ms);
    if (okB) sl += (double)expf(vB - ms);
#pragma unroll
    for (int mm = 1; mm < 64; mm <<= 1) sl += __shfl_xor(sl, mm, 64);
    if (ct == 0) {
      const int row = rowU + ri;
      SRec* rec = &sbuf[(size_t)row * NSTR + s];
#pragma unroll
      for (int jj = 0; jj < 4; ++jj) { rec->v[jj] = v[jj]; rec->ix[jj] = ix[jj]; }
      rec->ms = ms;
      rec->S = sl;
    }
  }
}

// Merge a sorted-4 list into a sorted-8 list (keep top-8).
__device__ inline void merge84(float* v, int* ix, const float* ov, const int* oix) {
  float rv[8]; int rix[8];
  int a = 0, b = 0;
#pragma unroll
  for (int t = 0; t < 8; ++t) {
    bool ta;
    if (a >= 8) ta = false;
    else if (b >= 4) ta = true;
    else ta = (v[a] > ov[b]) || (v[a] == ov[b] && ix[a] < oix[b]);
    if (ta) { rv[t] = v[a]; rix[t] = ix[a]; ++a; }
    else    { rv[t] = ov[b]; rix[t] = oix[b]; ++b; }
  }
#pragma unroll
  for (int t = 0; t < 8; ++t) { v[t] = rv[t]; ix[t] = rix[t]; }
}

__device__ inline void merge88(float* v, int* ix, const float* ov, const int* oix) {
  float rv[8]; int rix[8];
  int a = 0, b = 0;
#pragma unroll
  for (int t = 0; t < 8; ++t) {
    bool ta;
    if (a >= 8) ta = false;
    else if (b >= 8) ta = true;
    else ta = (v[a] > ov[b]) || (v[a] == ov[b] && ix[a] < oix[b]);
    if (ta) { rv[t] = v[a]; rix[t] = ix[a]; ++a; }
    else    { rv[t] = ov[b]; rix[t] = oix[b]; ++b; }
  }
#pragma unroll
  for (int t = 0; t < 8; ++t) { v[t] = rv[t]; ix[t] = rix[t]; }
}

// Per row: global top-8 by raw value, fp64 Z, then emulate fp32 log_softmax
// q = fl32(fl32(v-m) - L32) and output top-4 by (q desc, idx asc).
__global__ __launch_bounds__(64) void k_merge(const SRec* __restrict__ sbuf,
                                              float* __restrict__ topq,
                                              int* __restrict__ topi) {
  const int row = blockIdx.x;
  const int l = threadIdx.x;
  float lv[8]; int li[8];
#pragma unroll
  for (int jj = 0; jj < 8; ++jj) { lv[jj] = -INFINITY; li[jj] = 0x7fffffff; }
  float lms[7]; double lS[7];
  int ns = 0;
  for (int s = l; s < NSTR; s += 64) {
    const SRec* rec = &sbuf[(size_t)row * NSTR + s];
    float mv[4]; int mi[4];
#pragma unroll
    for (int jj = 0; jj < 4; ++jj) { mv[jj] = rec->v[jj]; mi[jj] = rec->ix[jj]; }
    lms[ns] = rec->ms;
    lS[ns] = rec->S;
    ++ns;
    merge84(lv, li, mv, mi);
  }
#pragma unroll
  for (int m = 1; m < 64; m <<= 1) {
    float ov[8]; int oi[8];
#pragma unroll
    for (int jj = 0; jj < 8; ++jj) {
      ov[jj] = __shfl_xor(lv[jj], m, 64);
      oi[jj] = __shfl_xor(li[jj], m, 64);
    }
    merge88(lv, li, ov, oi);
  }
  const float mg = lv[0];  // global max logit
  double Z = 0.0;
  for (int i = 0; i < ns; ++i) Z += lS[i] * (double)expf(lms[i] - mg);
#pragma unroll
  for (int m = 1; m < 64; m <<= 1) Z += __shfl_xor(Z, m, 64);
  const float Zf = (float)Z;
  const float L32 = (float)log((double)Zf);
  // fp32-quantized logp for top-8, re-sort by (q desc, idx asc)
  float q[8];
#pragma unroll
  for (int jj = 0; jj < 8; ++jj) {
    float g = lv[jj] - mg;   // fp32 sub
    q[jj] = g - L32;         // fp32 sub -> the ref's logp quantization
  }
  // insertion sort of 8 (full order comparator: q desc, idx asc)
  float sq[8]; int si[8];
#pragma unroll
  for (int jj = 0; jj < 8; ++jj) {
    float cv = q[jj]; int ci = li[jj];
    int pos = jj;
    for (int kk2 = 0; kk2 < jj; ++kk2) {
      if (cv > sq[kk2] || (cv == sq[kk2] && ci < si[kk2])) { pos = kk2; break; }
    }
    for (int kk2 = jj; kk2 > pos; --kk2) { sq[kk2] = sq[kk2 - 1]; si[kk2] = si[kk2 - 1]; }
    sq[pos] = cv; si[pos] = ci;
  }
  if (l == 0) {
#pragma unroll
    for (int jj = 0; jj < 4; ++jj) {
      topq[row * 4 + jj] = sq[jj];
      topi[row * 4 + jj] = si[jj];
    }
  }
}

// Fused beam transition + sequence gather (one launch instead of two).
// Threads 0..63: k_beam logic (trans top-4, stable flat-index ties),
// results published via LDS; after barrier all 256 threads do the
// sequence copy + append (k_seq logic).
__global__ __launch_bounds__(256) void k_beamseq(const float* __restrict__ topq,
                                                 const int* __restrict__ topi,
                                                 float* __restrict__ scores,
                                                 int* __restrict__ curx,
                                                 int* __restrict__ bfrom,
                                                 const int* __restrict__ src,
                                                 int* __restrict__ dst,
                                                 int t, int T) {
  const int tid = threadIdx.x;
  __shared__ int sh_bf[RR];
  __shared__ int sh_cx[RR];

  if (tid < 64) {
    const int b = tid;  // 0..63
    float sc[4];
#pragma unroll
    for (int f = 0; f < 4; ++f) sc[f] = scores[f * 64 + b];
    float tv[16];
#pragma unroll
    for (int f = 0; f < 4; ++f)
#pragma unroll
      for (int to = 0; to < 4; ++to)
        tv[f * 4 + to] = sc[f] + topq[(f * 64 + b) * 4 + to];  // fp32 add

    float ov[4]; int ord[4]; int cnt = 0;
#pragma unroll
    for (int flat = 0; flat < 16; ++flat) {
      float v = tv[flat];
      int pos = -1;
      for (int j = 0; j < cnt; ++j)
        if (v > ov[j]) { pos = j; break; }   // strict: stable on equals
      if (pos < 0) {
        if (cnt < 4) { ov[cnt] = v; ord[cnt] = flat; ++cnt; }
      } else {
        int last = (cnt < 4) ? cnt : 3;
        for (int j = last; j > pos; --j) { ov[j] = ov[j - 1]; ord[j] = ord[j - 1]; }
        ov[pos] = v; ord[pos] = flat;
        if (cnt < 4) ++cnt;
      }
    }
#pragma unroll
    for (int s = 0; s < 4; ++s) {
      int flat = ord[s];
      int f = flat >> 2, to = flat & 3;
      int tok = topi[(f * 64 + b) * 4 + to];
      scores[s * 64 + b] = ov[s];
      curx[s * 64 + b] = tok;
      bfrom[s * 64 + b] = f;
      sh_bf[s * 64 + b] = f;
      sh_cx[s * 64 + b] = tok;
    }
  }
  __syncthreads();

  const int s2 = tid >> 6, b2 = tid & 63;
  const int bf2 = sh_bf[s2 * 64 + b2];
  for (int u = 0; u < t; ++u)
    dst[(b2 * KK + s2) * T + u] = src[(b2 * KK + bf2) * T + u];
  dst[(b2 * KK + s2) * T + t] = sh_cx[s2 * 64 + b2];
}

__global__ __launch_bounds__(256) void k_out(const int* __restrict__ seqs,
                                             int* __restrict__ outp, int T) {
  int idx = blockIdx.x * 256 + threadIdx.x;
  if (idx < BB * T) {
    int b = idx / T, u = idx % T;
    outp[b * T + u] = seqs[(b * KK + 0) * T + u];
  }
}

extern "C" void kernel_launch(void* const* d_in, const int* in_sizes, int n_in,
                              void* d_out, int out_size, void* d_ws, size_t ws_size,
                              hipStream_t stream) {
  (void)in_sizes; (void)n_in; (void)ws_size;
  const int* xs = (const int*)d_in[0];
  const float* Etab = (const float*)d_in[1];
  const float* Wih = (const float*)d_in[2];
  const float* Whh = (const float*)d_in[3];
  const float* bih = (const float*)d_in[4];
  const float* bhh = (const float*)d_in[5];
  const float* Wout = (const float*)d_in[6];
  const float* bout = (const float*)d_in[7];
  int* outp = (int*)d_out;
  const int T = out_size / BB;  // 16

  // workspace carve (~6 MB)
  SRec* sbuf = (SRec*)d_ws;                       // 256*393*48 B
  float* hA = (float*)(sbuf + (size_t)RR * NSTR); // h double-buffer A
  float* hB = hA + (size_t)HH * RR;               // h double-buffer B
  float* topq = hB + (size_t)HH * RR;             // RR*4 f
  int* topi = (int*)(topq + RR * 4);              // RR*4 i
  float* scores = (float*)(topi + RR * 4);        // RR f
  int* curx = (int*)(scores + RR);                // RR i
  int* bfrom = curx + RR;                         // RR i
  int* seqA = bfrom + RR;                         // BB*KK*T i
  int* seqB = seqA + BB * KK * T;                 // BB*KK*T i

  k_init<<<dim3(512), dim3(256), 0, stream>>>(xs, hA, scores, curx, bfrom);
  for (int t = 0; t < T; ++t) {
    int* ssrc = (t % 2 == 0) ? seqA : seqB;
    int* sdst = (t % 2 == 0) ? seqB : seqA;
    float* hin = (t & 1) ? hB : hA;   // previous step's (ungathered) h
    float* hout = (t & 1) ? hA : hB;  // this step's new h
    k_gru<<<dim3(256), dim3(256), 0, stream>>>(Etab, Wih, Whh, bih, bhh,
                                               hin, hout, curx, bfrom);
    k_logits<<<dim3(3200), dim3(256), 0, stream>>>(Wout, bout, hout, sbuf);
    k_merge<<<dim3(RR), dim3(64), 0, stream>>>(sbuf, topq, topi);
    k_beamseq<<<dim3(1), dim3(256), 0, stream>>>(topq, topi, scores, curx,
                                                 bfrom, ssrc, sdst, t, T);
  }
  int* sfin = (T % 2 == 0) ? seqA : seqB;
  k_out<<<dim3((BB * T + 255) / 256), dim3(256), 0, stream>>>(sfin, outp, T);
}